// Round 4
// baseline (315.819 us; speedup 1.0000x reference)
//
#include <hip/hip_runtime.h>
#include <math.h>

// Problem shape (fixed by reference setup_inputs):
//   features:  (B=8, N=65536, C=64) fp32
//   coarse_map:(B=8, NP=16384, NS=32) int32 in [0, N)
//   out:       (B, NP, C) fp32 = max over NS gathered rows
constexpr int B  = 8;
constexpr int N  = 65536;
constexpr int C  = 64;      // floats per feature row (256 B)
constexpr int NP = 16384;
constexpr int NS = 32;
constexpr int C4 = C / 4;   // 16 float4 per row

// R4: R0/R1 were latency-bound (46% HBM, VALU 7%, ~0.56 loads in flight per
// thread) because each sample's chain was ds_bpermute -> addr -> load -> fmax,
// serial. R2 (asm loads) / R3 (sched_barrier) both lost their container, so
// this round uses ONLY plain-HIP constructs and fixes the chain structurally:
//   * 4 lanes per point; lane j owns channels [16j, 16j+16) = 4 float4 loads
//     per sample sharing ONE base address -> natural >=4-wide MLP even under
//     the most conservative sink-to-consumer schedule.
//   * indices via direct int4 loads (all 4 lanes read the same 16 B ->
//     wave broadcast, one transaction) -> no __shfl, no lgkmcnt in the chain.

__device__ __forceinline__ void gather_one(const float4* __restrict__ fbase,
                                           int idx,
                                           float4& m0, float4& m1,
                                           float4& m2, float4& m3)
{
    const float4* p = fbase + (size_t)idx * C4;
    const float4 a = p[0];
    const float4 b = p[1];
    const float4 c = p[2];
    const float4 d = p[3];
    m0.x = fmaxf(m0.x, a.x); m0.y = fmaxf(m0.y, a.y);
    m0.z = fmaxf(m0.z, a.z); m0.w = fmaxf(m0.w, a.w);
    m1.x = fmaxf(m1.x, b.x); m1.y = fmaxf(m1.y, b.y);
    m1.z = fmaxf(m1.z, b.z); m1.w = fmaxf(m1.w, b.w);
    m2.x = fmaxf(m2.x, c.x); m2.y = fmaxf(m2.y, c.y);
    m2.z = fmaxf(m2.z, c.z); m2.w = fmaxf(m2.w, c.w);
    m3.x = fmaxf(m3.x, d.x); m3.y = fmaxf(m3.y, d.y);
    m3.z = fmaxf(m3.z, d.z); m3.w = fmaxf(m3.w, d.w);
}

__global__ __launch_bounds__(256) void gather_max_kernel(
    const float4* __restrict__ feat,   // B*N*C4 float4
    const int4*   __restrict__ cmap4,  // B*NP*(NS/4) int4
    float4*       __restrict__ out)    // B*NP*C4 float4
{
    const int tid   = blockIdx.x * blockDim.x + threadIdx.x;
    const int point = tid >> 2;            // global point id in [0, B*NP)
    const int j     = tid & 3;             // lane-within-group; owns float4s [4j, 4j+4)
    if (point >= B * NP) return;

    const int     b     = point >> 14;     // point / NP (NP = 16384 = 2^14)
    const float4* fbase = feat + (size_t)b * N * C4 + j * 4;

    const int4* cbase = cmap4 + (size_t)point * (NS / 4);

    float4 m0 = make_float4(-INFINITY, -INFINITY, -INFINITY, -INFINITY);
    float4 m1 = m0, m2 = m0, m3 = m0;

#pragma unroll
    for (int ss = 0; ss < NS / 4; ++ss) {
        // All 4 lanes of the group read the same int4 -> wave-level broadcast.
        const int4 idx4 = cbase[ss];
        gather_one(fbase, idx4.x, m0, m1, m2, m3);
        gather_one(fbase, idx4.y, m0, m1, m2, m3);
        gather_one(fbase, idx4.z, m0, m1, m2, m3);
        gather_one(fbase, idx4.w, m0, m1, m2, m3);
    }

    // Lane stores its 4 consecutive float4s: 256 B contiguous per point.
    float4* o = out + (size_t)point * C4 + j * 4;
    o[0] = m0;
    o[1] = m1;
    o[2] = m2;
    o[3] = m3;
}

extern "C" void kernel_launch(void* const* d_in, const int* in_sizes, int n_in,
                              void* d_out, int out_size, void* d_ws, size_t ws_size,
                              hipStream_t stream) {
    const float4* feat  = (const float4*)d_in[0];
    const int4*   cmap4 = (const int4*)d_in[1];
    float4*       out   = (float4*)d_out;

    const int totalThreads = B * NP * 4;          // 4 lanes per point
    const int block = 256;
    const int grid  = (totalThreads + block - 1) / block;  // 2048
    gather_max_kernel<<<grid, block, 0, stream>>>(feat, cmap4, out);
}

// Round 5
// 274.756 us; speedup vs baseline: 1.1494x; 1.1494x over previous
//
#include <hip/hip_runtime.h>
#include <math.h>

// Problem shape (fixed by reference setup_inputs):
//   features:  (B=8, N=65536, C=64) fp32
//   coarse_map:(B=8, NP=16384, NS=32) int32 in [0, N)
//   out:       (B, NP, C) fp32 = max over NS gathered rows
constexpr int B  = 8;
constexpr int N  = 65536;
constexpr int C  = 64;      // floats per feature row (256 B)
constexpr int NP = 16384;
constexpr int NS = 32;
constexpr int C4 = C / 4;   // 16 float4 per row

// R5 (= R3 retried on healthy infra): R0/R1/R4 all latency-bound at ~0.6
// loads in flight per thread (VGPR pinned at 36 -- scheduler sinks each load
// to its consumer). R4 additionally showed the 4-lane/64B-granule pattern is
// WORSE (FETCH +78 MB, BW -11%), so we keep the 16-lane/256B decomposition.
// This round: 8-deep double-buffered gather pipeline enforced with
// __builtin_amdgcn_sched_barrier(0) region splits around COMPILER-TRACKED
// loads; SIInsertWaitcnts emits the counted vmcnt waits itself. No inline
// asm, no manual waitcnt -- cannot hang by construction.

template <int G>
__device__ __forceinline__ void issue_batch(const float4* __restrict__ fbase,
                                            int2 myIdx, int gbase, int j,
                                            float4 (&f)[8])
{
#pragma unroll
    for (int u = 0; u < 8; ++u) {
        const int s   = G * 8 + u;
        const int v   = (s & 1) ? myIdx.y : myIdx.x;
        const int idx = __shfl(v, gbase + (s >> 1), 64);
        f[u] = fbase[(size_t)idx * C4 + j];
    }
    // Region split: the 8 loads above may not sink below this point, and no
    // consumer may hoist above it -> all 8 stay issued back-to-back.
    __builtin_amdgcn_sched_barrier(0);
}

__device__ __forceinline__ void reduce_batch(const float4 (&f)[8], float4& m)
{
#pragma unroll
    for (int u = 0; u < 8; ++u) {
        m.x = fmaxf(m.x, f[u].x);
        m.y = fmaxf(m.y, f[u].y);
        m.z = fmaxf(m.z, f[u].z);
        m.w = fmaxf(m.w, f[u].w);
    }
}

// 16 lanes cooperate on one output point; lane j owns channels [4j, 4j+4).
// Each gathered row read = 16 lanes x float4 = one contiguous 256 B segment.
__global__ __launch_bounds__(256, 4) void gather_max_kernel(
    const float4* __restrict__ feat,   // B*N*C4 float4
    const int*    __restrict__ cmap,   // B*NP*NS int32
    float4*       __restrict__ out)    // B*NP*C4 float4
{
    const int tid   = blockIdx.x * blockDim.x + threadIdx.x;
    const int point = tid >> 4;            // global point id in [0, B*NP)
    const int j     = tid & 15;            // lane-within-group = float4 index
    if (point >= B * NP) return;

    const int     b     = point >> 14;     // point / NP (NP = 16384 = 2^14)
    const float4* fbase = feat + (size_t)b * N * C4;

    // Cooperative index load: lane j holds idx[2j], idx[2j+1] (coalesced 128 B/group).
    const int2 myIdx = ((const int2*)(cmap + (size_t)point * NS))[j];

    const int lane  = threadIdx.x & 63;
    const int gbase = lane & ~15;          // base lane of this 16-lane group

    float4 m = make_float4(-INFINITY, -INFINITY, -INFINITY, -INFINITY);

    float4 fA[8], fB[8];

    // Software pipeline: 4 batches of 8 samples, 2 batches (16 loads) in flight.
    issue_batch<0>(fbase, myIdx, gbase, j, fA);
    issue_batch<1>(fbase, myIdx, gbase, j, fB);

    reduce_batch(fA, m);                         // compiler waits vmcnt(8)
    issue_batch<2>(fbase, myIdx, gbase, j, fA);

    reduce_batch(fB, m);                         // vmcnt(8)
    issue_batch<3>(fbase, myIdx, gbase, j, fB);

    reduce_batch(fA, m);                         // vmcnt(8)
    reduce_batch(fB, m);                         // vmcnt(0)

    // Coalesced float4 store: consecutive lanes -> consecutive float4s.
    out[(size_t)point * C4 + j] = m;
}

extern "C" void kernel_launch(void* const* d_in, const int* in_sizes, int n_in,
                              void* d_out, int out_size, void* d_ws, size_t ws_size,
                              hipStream_t stream) {
    const float4* feat = (const float4*)d_in[0];
    const int*    cmap = (const int*)d_in[1];
    float4*       out  = (float4*)d_out;

    const int totalThreads = B * NP * 16;         // 16 lanes per point
    const int block = 256;
    const int grid  = (totalThreads + block - 1) / block;  // 8192
    gather_max_kernel<<<grid, block, 0, stream>>>(feat, cmap, out);
}